// Round 2
// baseline (9361.877 us; speedup 1.0000x reference)
//
#include <hip/hip_runtime.h>
#include <stdint.h>

// SpikingNetwork B=128 T=128 I=1024 dims 2048/2048/1024, beta=0.9, thr=1.0.
// R6: arithmetic-intensity rework. 512 blocks x 256 thr, tiles 64m x 64n,
// per-thread 4m x 4n (16 FMA per 2 ds_read_b128). Each block computes ONE
// 512-k fmac chain (4 chunks x 128k); L0 ksplit2 (128 blk), L1 ksplit4 (256),
// L2 ksplit4 (128) -> equal work. DAG identical to R5: per-output sequential
// fmac over each 512-chain, owner merges ((P0+P1)+P2)+P3 ascending (__fadd_rn).
// Both lA and lB in [k][col^fswz] layout (XOR swizzle, b128 reads). Register
// prefetch: next chunk's global loads issued before FMA loop (T14 async-split).
// Spikes cross layers as bitmasks; fp32 partials; agent-scope atomics.

#define TT   128
#define NB   128
#define DD2  1024

// ws layout (u32 units)
#define SPK0_OFF 0u
#define SPK1_OFF (128u*128u*64u)                 // 1,048,576
#define PART_OFF (2u*128u*128u*64u)              // 2,097,152
#define NHELP    352u
#define FLG_OFF  (PART_OFF + NHELP*4096u)        // 3,538,944
// flg: pflag[384] (hslot-indexed), oflag[192] (ownerid), done0[2][128], done1[2][128]
#define NFLG     1088u
#define WS_NEED_BYTES ((size_t)(FLG_OFF + NFLG) * 4u)   // 14,160,128 (<= R4-proven)

__device__ __forceinline__ void wait_ge(uint32_t* p, uint32_t tgt){
  while (__hip_atomic_load(p, __ATOMIC_ACQUIRE, __HIP_MEMORY_SCOPE_AGENT) < tgt)
    __builtin_amdgcn_s_sleep(1);
}

// LDS column swizzle: keeps 4-float granules (b128-aligned); constant over
// k within a 4-aligned granule.
__device__ __forceinline__ int fswz(int k){
  return (k & 16) | ((k ^ (k >> 3)) & 12);
}

__global__ void sentinel_kernel(float* o){ o[0] = 42.0f; }   // ws-too-small marker

__global__ __launch_bounds__(256, 2) void snn_kernel(
    const float* __restrict__ x,
    const float* __restrict__ W0, const float* __restrict__ b0,
    const float* __restrict__ W1, const float* __restrict__ b1,
    const float* __restrict__ W2, const float* __restrict__ b2,
    float* __restrict__ out, uint32_t* __restrict__ ws)
{
  __shared__ __align__(16) float lA[128][68];   // [k][m^swz], 34,816 B
  __shared__ __align__(16) float lB[128][68];   // [k][n^swz], 34,816 B
  __shared__ uint32_t lBits[128];               // 64 rows x 2 spike words

  const int tid = threadIdx.x;
  const int tm  = tid & 15;      // m-group: rows tm*4 .. +3
  const int tn  = tid >> 4;      // n-group: cols tn*4 .. +3
  const int bid = blockIdx.x;

  uint32_t* spikes0  = ws + SPK0_OFF;
  uint32_t* spikes1  = ws + SPK1_OFF;
  float*    partials = (float*)(ws + PART_OFF);   // [NHELP][4096]
  uint32_t* flg   = ws + FLG_OFF;
  uint32_t* pflag = flg;            // [384] helper(hslot)->owner: partials for t ready
  uint32_t* oflag = flg + 384;      // [192] owner(ownerid)->helpers: consumed through t
  uint32_t* done0 = flg + 576;      // [2][128] per m-half, target 32
  uint32_t* done1 = flg + 832;      // [2][128]

  int group, kp, tl, m0, n0, K, ksp, hslot, ownerid;
  const float *Wl, *bl;
  const uint32_t* spkIn; uint32_t* spkOut;
  uint32_t *dIn, *dOut;
  if (bid < 128) {          // L0: out 128x2048, K=1024, ksplit2
    group=0; ksp=2; int rel=bid;      kp=rel&1; tl=rel>>1;
    m0=(tl>>5)*64; n0=(tl&31)*64; K=1024; Wl=W0; bl=b0;
    spkIn=nullptr;  spkOut=spikes0;
    dIn=nullptr;               dOut=done0 + (m0>>6)*128;
    hslot = kp ? tl : -1; ownerid = tl;
  } else if (bid < 384) {   // L1: out 128x2048, K=2048, ksplit4
    group=1; ksp=4; int rel=bid-128;  kp=rel&3; tl=rel>>2;
    m0=(tl>>5)*64; n0=(tl&31)*64; K=2048; Wl=W1; bl=b1;
    spkIn=spikes0;  spkOut=spikes1;
    dIn=done0 + (m0>>6)*128;   dOut=done1 + (m0>>6)*128;
    hslot = kp ? (64 + tl*3 + (kp-1)) : -1; ownerid = 64 + tl;
  } else {                  // L2: out 128x1024, K=2048, ksplit4
    group=2; ksp=4; int rel=bid-384;  kp=rel&3; tl=rel>>2;
    m0=(tl>>4)*64; n0=(tl&15)*64; K=2048; Wl=W2; bl=b2;
    spkIn=spikes1;  spkOut=nullptr;
    dIn=done1 + (m0>>6)*128;   dOut=nullptr;
    hslot = kp ? (256 + tl*3 + (kp-1)) : -1; ownerid = 128 + tl;
  }
  const bool owner = (kp == 0);
  const int  K0    = kp * 512;

  float bias[4];
  #pragma unroll
  for (int c = 0; c < 4; ++c) bias[c] = bl[n0 + tn*4 + c];

  float vst[4][4];   // membrane potential in registers across all T (owners)
  #pragma unroll
  for (int r = 0; r < 4; ++r)
    #pragma unroll
    for (int c = 0; c < 4; ++c) vst[r][c] = 0.f;

  // staging decompositions (loop-invariant)
  const int s_row = tid >> 5;       // +it*8 gives row 0..63
  const int s_kq  = tid & 31;       // float4 index along k (0..31)
  // spike-expansion mapping
  const int e_mq   = tid & 15;      // row quad e_mq*4..+3
  const int e_sub  = tid >> 4;
  const int e_wsub = e_sub & 3;     // which 32-bit word in chunk
  const int e_kq8  = e_sub >> 2;    // which 8-k octet of that word
  const int e_kloc = e_wsub*32 + e_kq8*8;

  float4   ra[8];     // prefetched A chunk (group 0)
  uint32_t rw[4];     // prefetched spike words (group 1/2)
  float4   rb[8];     // prefetched B chunk

  for (int t = 0; t < TT; ++t) {
    if (dIn) {  // previous layer's spikes for this m-half must be complete
      if (tid == 0) wait_ge(&dIn[t], 32u);
      __syncthreads();
    }

    float acc[4][4];
    #pragma unroll
    for (int r = 0; r < 4; ++r)
      #pragma unroll
      for (int c = 0; c < 4; ++c) acc[r][c] = 0.f;

#define LOAD_REGS(CH) do {                                                     \
      const int kb_ = K0 + (CH)*128;                                           \
      _Pragma("unroll")                                                        \
      for (int it = 0; it < 8; ++it)                                           \
        rb[it] = *(const float4*)(Wl + (size_t)(n0 + s_row + it*8)*K + kb_ + s_kq*4); \
      if (group == 0) {                                                        \
        _Pragma("unroll")                                                      \
        for (int it = 0; it < 8; ++it)                                         \
          ra[it] = *(const float4*)(x + ((size_t)(m0 + s_row + it*8)*TT + t)*1024 + kb_ + s_kq*4); \
      } else {                                                                 \
        const size_t rb_ = ((size_t)t*NB + m0 + e_mq*4)*64 + (kb_>>5) + e_wsub; \
        _Pragma("unroll")                                                      \
        for (int j = 0; j < 4; ++j)                                            \
          rw[j] = __hip_atomic_load(&spkIn[rb_ + (size_t)j*64],                \
                                    __ATOMIC_RELAXED, __HIP_MEMORY_SCOPE_AGENT); \
      }                                                                        \
    } while (0)

    LOAD_REGS(0);

    #pragma unroll 1
    for (int ch = 0; ch < 4; ++ch) {
      // ---- write prefetched regs -> LDS (swizzled)
      {
        const int k0 = s_kq*4;
        const int sw = fswz(k0);
        #pragma unroll
        for (int it = 0; it < 8; ++it) {
          const int col = (s_row + it*8) ^ sw;
          lB[k0+0][col] = rb[it].x; lB[k0+1][col] = rb[it].y;
          lB[k0+2][col] = rb[it].z; lB[k0+3][col] = rb[it].w;
        }
        if (group == 0) {
          #pragma unroll
          for (int it = 0; it < 8; ++it) {
            const int col = (s_row + it*8) ^ sw;
            lA[k0+0][col] = ra[it].x; lA[k0+1][col] = ra[it].y;
            lA[k0+2][col] = ra[it].z; lA[k0+3][col] = ra[it].w;
          }
        } else {
          #pragma unroll
          for (int i = 0; i < 8; ++i) {
            const int k  = e_kloc + i;
            const int sh = k & 31;
            float4 f;
            f.x = ((rw[0] >> sh) & 1u) ? 1.0f : 0.0f;
            f.y = ((rw[1] >> sh) & 1u) ? 1.0f : 0.0f;
            f.z = ((rw[2] >> sh) & 1u) ? 1.0f : 0.0f;
            f.w = ((rw[3] >> sh) & 1u) ? 1.0f : 0.0f;
            *(float4*)&lA[k][(e_mq*4) ^ fswz(k)] = f;
          }
        }
      }
      __syncthreads();

      if (ch < 3) {   // issue next chunk's global loads; latency hides under FMA
        switch (ch) { case 0: LOAD_REGS(1); break;
                      case 1: LOAD_REGS(2); break;
                      default: LOAD_REGS(3); break; }
      }

      // ---- FMA micro-kernel: 128 k x (4m x 4n), sequential ascending k
      #pragma unroll 4
      for (int k4 = 0; k4 < 32; ++k4) {
        const int kbase = k4*4;
        const int sw  = fswz(kbase);          // constant over the 4 sub-ks
        const float* pa = &lA[kbase][(tm*4) ^ sw];
        const float* pb = &lB[kbase][(tn*4) ^ sw];
        #pragma unroll
        for (int u = 0; u < 4; ++u) {
          const float4 a = *(const float4*)(pa + u*68);
          const float4 b = *(const float4*)(pb + u*68);
          acc[0][0] = __builtin_fmaf(a.x, b.x, acc[0][0]);
          acc[1][0] = __builtin_fmaf(a.y, b.x, acc[1][0]);
          acc[2][0] = __builtin_fmaf(a.z, b.x, acc[2][0]);
          acc[3][0] = __builtin_fmaf(a.w, b.x, acc[3][0]);
          acc[0][1] = __builtin_fmaf(a.x, b.y, acc[0][1]);
          acc[1][1] = __builtin_fmaf(a.y, b.y, acc[1][1]);
          acc[2][1] = __builtin_fmaf(a.z, b.y, acc[2][1]);
          acc[3][1] = __builtin_fmaf(a.w, b.y, acc[3][1]);
          acc[0][2] = __builtin_fmaf(a.x, b.z, acc[0][2]);
          acc[1][2] = __builtin_fmaf(a.y, b.z, acc[1][2]);
          acc[2][2] = __builtin_fmaf(a.z, b.z, acc[2][2]);
          acc[3][2] = __builtin_fmaf(a.w, b.z, acc[3][2]);
          acc[0][3] = __builtin_fmaf(a.x, b.w, acc[0][3]);
          acc[1][3] = __builtin_fmaf(a.y, b.w, acc[1][3]);
          acc[2][3] = __builtin_fmaf(a.z, b.w, acc[2][3]);
          acc[3][3] = __builtin_fmaf(a.w, b.w, acc[3][3]);
        }
      }
      __syncthreads();
    }
#undef LOAD_REGS

    if (!owner) {
      // single-buffered partials: wait until owner consumed t-1 before overwrite
      if (t >= 1) { if (tid == 0) wait_ge(&oflag[ownerid], (uint32_t)t); __syncthreads(); }
      uint64_t* pb = (uint64_t*)(partials + (size_t)hslot*4096) + tid*8;
      #pragma unroll
      for (int r = 0; r < 4; ++r)
        #pragma unroll
        for (int cq = 0; cq < 2; ++cq) {
          union { float f[2]; uint64_t u; } cv;
          cv.f[0] = acc[r][cq*2+0]; cv.f[1] = acc[r][cq*2+1];
          __hip_atomic_store(&pb[r*2+cq], cv.u, __ATOMIC_RELAXED, __HIP_MEMORY_SCOPE_AGENT);
        }
      __syncthreads();
      if (tid == 0) __hip_atomic_store(&pflag[hslot], (uint32_t)(t+1), __ATOMIC_RELEASE, __HIP_MEMORY_SCOPE_AGENT);
      continue;
    }

    // owner: gather k-helper partials in ascending-k order (deterministic DAG)
    if (ksp > 1) {
      if (tid == 0)
        for (int p = 1; p < ksp; ++p) {
          int hs = (group==0) ? tl : ((group==1) ? (64 + tl*3 + (p-1)) : (256 + tl*3 + (p-1)));
          wait_ge(&pflag[hs], (uint32_t)(t+1));
        }
      __syncthreads();
      for (int p = 1; p < ksp; ++p) {
        int hs = (group==0) ? tl : ((group==1) ? (64 + tl*3 + (p-1)) : (256 + tl*3 + (p-1)));
        uint64_t* pb = (uint64_t*)(partials + (size_t)hs*4096) + tid*8;
        #pragma unroll
        for (int r = 0; r < 4; ++r)
          #pragma unroll
          for (int cq = 0; cq < 2; ++cq) {
            union { uint64_t u; float f[2]; } cv;
            cv.u = __hip_atomic_load(&pb[r*2+cq], __ATOMIC_RELAXED, __HIP_MEMORY_SCOPE_AGENT);
            acc[r][cq*2+0] = __fadd_rn(acc[r][cq*2+0], cv.f[0]);
            acc[r][cq*2+1] = __fadd_rn(acc[r][cq*2+1], cv.f[1]);
          }
      }
      __syncthreads();
      if (tid == 0) __hip_atomic_store(&oflag[ownerid], (uint32_t)(t+1), __ATOMIC_RELEASE, __HIP_MEMORY_SCOPE_AGENT);
    }

    if (group < 2) { if (tid < 128) lBits[tid] = 0; __syncthreads(); }

    // LIF: cur = acc + b (rn); v = 0.9*v + cur (mul+add rn, NO fma contraction,
    // matching np's BETA*vi + cur); spk = v > 1.0 strictly; v -= spk.
    float sv[4][4], vv8[4][4];
    #pragma unroll
    for (int r = 0; r < 4; ++r) {
      uint32_t msk = 0;
      #pragma unroll
      for (int c = 0; c < 4; ++c) {
        float cur = __fadd_rn(acc[r][c], bias[c]);
        float vv  = __fadd_rn(__fmul_rn(0.9f, vst[r][c]), cur);
        float s   = (vv > 1.0f) ? 1.0f : 0.0f;
        vv = __fsub_rn(vv, s);
        vst[r][c] = vv;
        sv[r][c] = s; vv8[r][c] = vv;
        msk |= (s != 0.f) ? (1u << ((tn&7)*4 + c)) : 0u;
      }
      if (group < 2 && msk) atomicOr(&lBits[(tm*4 + r)*2 + (tn>>3)], msk);
    }

    if (group == 2) {
      #pragma unroll
      for (int r = 0; r < 4; ++r) {
        size_t o  = ((size_t)(m0 + tm*4 + r)*TT + t)*DD2 + n0 + tn*4;
        *(float4*)(out + o)  = make_float4(sv[r][0], sv[r][1], sv[r][2], sv[r][3]);
        size_t ov = (size_t)NB*TT*DD2 + o;
        *(float4*)(out + ov) = make_float4(vv8[r][0], vv8[r][1], vv8[r][2], vv8[r][3]);
      }
    } else {
      __syncthreads();
      if (tid < 128)
        __hip_atomic_store(&spkOut[((size_t)t*NB + m0 + (tid>>1))*64 + (n0>>5) + (tid&1)],
                           lBits[tid], __ATOMIC_RELAXED, __HIP_MEMORY_SCOPE_AGENT);
      __syncthreads();
      if (tid == 0) __hip_atomic_fetch_add(&dOut[t], 1u, __ATOMIC_RELEASE, __HIP_MEMORY_SCOPE_AGENT);
    }
  }
}

extern "C" void kernel_launch(void* const* d_in, const int* in_sizes, int n_in,
                              void* d_out, int out_size, void* d_ws, size_t ws_size,
                              hipStream_t stream) {
  (void)in_sizes; (void)n_in; (void)out_size;
  float* outf = (float*)d_out;
  if (ws_size < WS_NEED_BYTES) {            // diagnostic: absmax ~41 => ws too small
    sentinel_kernel<<<1, 1, 0, stream>>>(outf);
    return;
  }
  const float* x  = (const float*)d_in[0];
  const float* W0 = (const float*)d_in[1];
  const float* b0 = (const float*)d_in[2];
  const float* W1 = (const float*)d_in[3];
  const float* b1 = (const float*)d_in[4];
  const float* W2 = (const float*)d_in[5];
  const float* b2 = (const float*)d_in[6];
  uint32_t* ws = (uint32_t*)d_ws;

  // zero flags (spikes/partials are write-before-read; flags gate everything)
  hipMemsetAsync(ws + FLG_OFF, 0, NFLG * sizeof(uint32_t), stream);

  snn_kernel<<<512, 256, 0, stream>>>(x, W0, b0, W1, b1, W2, b2, outf, ws);
}